// Round 10
// baseline (251.700 us; speedup 1.0000x reference)
//
#include <hip/hip_runtime.h>
#include <stdint.h>

typedef __bf16 bf16;
typedef float f32x4 __attribute__((ext_vector_type(4)));
typedef bf16 bf16x8 __attribute__((ext_vector_type(8)));
typedef bf16 bf16x4 __attribute__((ext_vector_type(4)));

#define MFMA16(a, b, c) __builtin_amdgcn_mfma_f32_16x16x32_bf16((a), (b), (c), 0, 0, 0)
#define EXP2F(x) __builtin_amdgcn_exp2f(x)

__device__ __forceinline__ void gll16(const void* g, void* l) {
  __builtin_amdgcn_global_load_lds((const __attribute__((address_space(1))) void*)g,
                                   (__attribute__((address_space(3))) void*)l, 16, 0, 0);
}

// ---------------------------------------------------------------------------
// fp32 -> bf16 conversion of WEIGHTS + E only (proj consumes Q/K/V fp32
// directly now). 294912 float4 = 1152 blocks.
// ---------------------------------------------------------------------------
__global__ __launch_bounds__(256) void convert_we(
    const float4* __restrict__ Wq, const float4* __restrict__ Wk,
    const float4* __restrict__ Wv, const float4* __restrict__ fcw,
    const float4* __restrict__ E, bf16x4* __restrict__ Wqb, bf16x4* __restrict__ Wkb,
    bf16x4* __restrict__ Wvb, bf16x4* __restrict__ fcb, bf16x4* __restrict__ Eb) {
  int i = blockIdx.x * 256 + threadIdx.x;
  const float4* s;
  bf16x4* d;
  int off;
  if (i < 65536) { s = Wq; d = Wqb; off = i; }
  else if (i < 131072) { s = Wk; d = Wkb; off = i - 65536; }
  else if (i < 196608) { s = Wv; d = Wvb; off = i - 131072; }
  else if (i < 262144) { s = fcw; d = fcb; off = i - 196608; }
  else { s = E; d = Eb; off = i - 262144; }
  float4 v = s[off];
  bf16x4 o;
  o[0] = (bf16)v.x; o[1] = (bf16)v.y; o[2] = (bf16)v.z; o[3] = (bf16)v.w;
  d[off] = o;
}

// ---------------------------------------------------------------------------
// proj_gemm: 128x64 tiles, grid (64, 8, 3) = 1536 blocks (6/CU).
// A = RAW FP32 activations (Q/K/V) staged via the R4-proven fp32 swizzle
// (16KB tile, 8 chunks/row, c^(r&7)), cast to bf16 at fragment build —
// numerically identical to pre-converting; eliminates 72MB convert traffic.
// B = bf16 weights (64x32 tile, 1 gll16/kt).
// z==0/1 write q/k in (B,H,L,64); z==2 (one head/block) writes v DIRECTLY
// TRANSPOSED into vT (B,H,64,L) via LDS-staged transpose.
// ---------------------------------------------------------------------------
__global__ __launch_bounds__(256) void proj_gemm(
    const float* __restrict__ Q, const float* __restrict__ K, const float* __restrict__ V,
    const bf16* __restrict__ Wq, const bf16* __restrict__ Wk, const bf16* __restrict__ Wv,
    const float* __restrict__ bq, const float* __restrict__ bk, const float* __restrict__ bv,
    bf16* __restrict__ qb, bf16* __restrict__ kb, bf16* __restrict__ vT) {
  __shared__ __align__(16) char smem[20480];  // A 16KB fp32 + B 4KB bf16; transpose 17.4KB
  char* ldsA = smem;
  char* ldsB = smem + 16384;
  const int z = blockIdx.z;
  const float* A = z == 0 ? Q : (z == 1 ? K : V);
  const bf16* W = z == 0 ? Wq : (z == 1 ? Wk : Wv);
  const float* bias = z == 0 ? bq : (z == 1 ? bk : bv);
  const int m0 = blockIdx.x * 128, n0 = blockIdx.y * 64;
  const int t = threadIdx.x;
  const int lane = t & 63, w = t >> 6;
  const int l15 = lane & 15, quad = lane >> 4;
  const int wm = w >> 1, wn = w & 1;
  f32x4 acc[4][2];
#pragma unroll
  for (int i = 0; i < 4; i++)
#pragma unroll
    for (int j = 0; j < 2; j++) acc[i][j] = (f32x4){0.f, 0.f, 0.f, 0.f};

  // A staging (fp32): 1024 chunks; slot t+256p -> row ar+32p, chunk ac.
  const int ar = t >> 3, ac = (t & 7) ^ (ar & 7);
  // B staging (bf16): 256 chunks; slot t -> row br, chunk bc.
  const int br = t >> 2, bc = (t & 3) ^ (br & 3);
  const int wbase = (t & 192) * 16;  // wave-uniform LDS base (+lane*16 by HW)

  int boff[2];
#pragma unroll
  for (int nt = 0; nt < 2; nt++) {
    int n = wn * 32 + nt * 16 + l15;
    boff[nt] = (n << 6) + ((quad ^ (n & 3)) << 4);
  }

  for (int kt = 0; kt < 512; kt += 32) {
#pragma unroll
    for (int p = 0; p < 4; p++)
      gll16(A + (size_t)(m0 + ar + 32 * p) * 512 + kt + ac * 4, ldsA + p * 4096 + wbase);
    gll16(W + (size_t)(n0 + br) * 512 + kt + bc * 8, ldsB + wbase);
    __syncthreads();
    bf16x8 af[4], bfr[2];
#pragma unroll
    for (int mt = 0; mt < 4; mt++) {
      int m = wm * 64 + mt * 16 + l15;
      const char* base = ldsA + (m << 7);
      float4 x0 = *(const float4*)(base + ((((quad << 1) | 0) ^ (m & 7)) << 4));
      float4 x1 = *(const float4*)(base + ((((quad << 1) | 1) ^ (m & 7)) << 4));
      bf16x8 v;
      v[0] = (bf16)x0.x; v[1] = (bf16)x0.y; v[2] = (bf16)x0.z; v[3] = (bf16)x0.w;
      v[4] = (bf16)x1.x; v[5] = (bf16)x1.y; v[6] = (bf16)x1.z; v[7] = (bf16)x1.w;
      af[mt] = v;
    }
#pragma unroll
    for (int nt = 0; nt < 2; nt++) bfr[nt] = *(const bf16x8*)(ldsB + boff[nt]);
#pragma unroll
    for (int mt = 0; mt < 4; mt++)
#pragma unroll
      for (int nt = 0; nt < 2; nt++)
        acc[mt][nt] = MFMA16(af[mt], bfr[nt], acc[mt][nt]);
    __syncthreads();
  }

  if (z == 2) {
    // ---- transposed epilogue: this block covers ONE head (64 d-cols) ----
    bf16* T = (bf16*)smem;  // [64][136]
    const int b = m0 >> 11, l0 = m0 & 2047, h0 = blockIdx.y;
#pragma unroll
    for (int mt = 0; mt < 4; mt++)
#pragma unroll
      for (int nt = 0; nt < 2; nt++) {
        int d = wn * 32 + nt * 16 + l15;
        int lloc = wm * 64 + mt * 16 + quad * 4;
        float bi = bias[n0 + d];
        bf16x4 pv;
#pragma unroll
        for (int r = 0; r < 4; r++) pv[r] = (bf16)(acc[mt][nt][r] + bi);
        *(bf16x4*)&T[d * 136 + lloc] = pv;
      }
    __syncthreads();
    bf16* dsth = vT + ((size_t)((b * 8 + h0) * 64)) * 2048 + l0;
#pragma unroll
    for (int p = 0; p < 4; p++) {
      int id = t + 256 * p;  // 1024 chunks: 64 d-rows x 16 l-chunks of 8
      int d = id >> 4, c = id & 15;
      bf16x8 v = *(const bf16x8*)&T[d * 136 + c * 8];
      *(bf16x8*)&dsth[(size_t)d * 2048 + c * 8] = v;
    }
  } else {
    bf16* out = z == 0 ? qb : kb;
#pragma unroll
    for (int mt = 0; mt < 4; mt++)
#pragma unroll
      for (int nt = 0; nt < 2; nt++)
#pragma unroll
        for (int r = 0; r < 4; r++) {
          int gm = m0 + wm * 64 + mt * 16 + quad * 4 + r;
          int gn = n0 + wn * 32 + nt * 16 + l15;
          float v = acc[mt][nt][r] + bias[gn];
          int b = gm >> 11, l = gm & 2047, h = gn >> 6, d = gn & 63;
          out[(((size_t)(b * 8 + h)) * 2048 + l) * 64 + d] = (bf16)v;
        }
  }
}

// ---------------------------------------------------------------------------
// final_gemm: 64x64 tiles, grid (128, 8) = 1024 blocks (4/CU; was 2/CU).
// Wave layout 2x2, wave tile 32x32, acc[2][2]; 1 gll16/side/kt.
// ---------------------------------------------------------------------------
__global__ __launch_bounds__(256) void final_gemm(const bf16* __restrict__ A,
                                                  const bf16* __restrict__ W,
                                                  const float* __restrict__ bias,
                                                  float* __restrict__ out) {
  __shared__ __align__(16) bf16 ldsA[64 * 32];
  __shared__ __align__(16) bf16 ldsB[64 * 32];
  const int m0 = blockIdx.x * 64, n0 = blockIdx.y * 64;
  const int t = threadIdx.x;
  const int lane = t & 63, w = t >> 6;
  const int l15 = lane & 15, quad = lane >> 4;
  const int wm = w >> 1, wn = w & 1;
  f32x4 acc[2][2];
#pragma unroll
  for (int i = 0; i < 2; i++)
#pragma unroll
    for (int j = 0; j < 2; j++) acc[i][j] = (f32x4){0.f, 0.f, 0.f, 0.f};

  const int r0 = t >> 2, c0 = (t & 3) ^ (r0 & 3);
  const int wbase = (t & 192) * 16;

  int aoff[2], boff[2];
#pragma unroll
  for (int mt = 0; mt < 2; mt++) {
    int m = wm * 32 + mt * 16 + l15;
    aoff[mt] = (m << 6) + ((quad ^ (m & 3)) << 4);
    int n = wn * 32 + mt * 16 + l15;
    boff[mt] = (n << 6) + ((quad ^ (n & 3)) << 4);
  }

  for (int kt = 0; kt < 512; kt += 32) {
    gll16(A + (size_t)(m0 + r0) * 512 + kt + c0 * 8, (char*)ldsA + wbase);
    gll16(W + (size_t)(n0 + r0) * 512 + kt + c0 * 8, (char*)ldsB + wbase);
    __syncthreads();
    bf16x8 af[2], bfr[2];
#pragma unroll
    for (int mt = 0; mt < 2; mt++) af[mt] = *(const bf16x8*)((const char*)ldsA + aoff[mt]);
#pragma unroll
    for (int nt = 0; nt < 2; nt++) bfr[nt] = *(const bf16x8*)((const char*)ldsB + boff[nt]);
#pragma unroll
    for (int mt = 0; mt < 2; mt++)
#pragma unroll
      for (int nt = 0; nt < 2; nt++)
        acc[mt][nt] = MFMA16(af[mt], bfr[nt], acc[mt][nt]);
    __syncthreads();
  }

#pragma unroll
  for (int mt = 0; mt < 2; mt++)
#pragma unroll
    for (int nt = 0; nt < 2; nt++)
#pragma unroll
      for (int r = 0; r < 4; r++) {
        int gm = m0 + wm * 32 + mt * 16 + quad * 4 + r;
        int gn = n0 + wn * 32 + nt * 16 + l15;
        out[(size_t)gm * 512 + gn] = acc[mt][nt][r] + bias[gn];
      }
}

// ---------------------------------------------------------------------------
// Flash attention + relative position, causal — exact R5/R0 structure (~90us).
// Epilogue change only: COMPLETE jobs (full strips, strip<16 — exactly the
// rows l<1024, which have a single chunk) normalize in-place by 1/Osum
// (skips Os0 write; one fewer bf16 round-trip). Rows >=1024 stay
// unnormalized, merged by the (halved) norm kernel.
// ---------------------------------------------------------------------------
__global__ __launch_bounds__(256, 4) void attn_kernel(
    const bf16* __restrict__ qbuf, const bf16* __restrict__ kbuf,
    const bf16* __restrict__ vT, const bf16* __restrict__ Eb,
    bf16* __restrict__ attnb, bf16* __restrict__ Of1,
    float* __restrict__ Os0, float* __restrict__ Os1) {
  __shared__ bf16 Kl[64 * 64];
  __shared__ bf16 Vl[64 * 64];
  __shared__ bf16 Pl[4][16 * 72];
  const int t = threadIdx.x, w = t >> 6, lane = t & 63;
  const int l15 = lane & 15, quad = lane >> 4;
  const int x = blockIdx.x;
  const int bh = x & 31, job = x >> 5;
  int strip, jt0, jt1;
  bool isB;
  if (job < 16) {
    strip = 16 + job; jt0 = 0; jt1 = 16; isB = false;
  } else {
    int k = job - 16, i = k >> 1;
    if ((k & 1) == 0) { strip = 15 - i; jt0 = 0; jt1 = 16 - i; isB = false; }
    else { strip = 31 - i; jt0 = 16; jt1 = 32 - i; isB = true; }
  }
  const int i0 = strip * 64 + w * 16;  // this wave's 16 q-rows
  bf16* Pw = Pl[w];
  const bf16* qh = qbuf + (size_t)bh * 2048 * 64;
  const bf16* kh = kbuf + (size_t)bh * 2048 * 64;
  const bf16* vh = vT + (size_t)bh * 64 * 2048;

  // staging: slot s holds (row = s>>3, chunk = (s&7)^(row&7)); thread t does
  // slots t and t+256; wave-uniform LDS byte base + lane*16B.
  const int sr0 = t >> 3, sc0 = (t & 7) ^ (sr0 & 7);
  const int sr1 = sr0 + 32;
  const int wb0 = (t & 192) * 16;  // byte offset of this wave's slot group
  const int wb1 = 4096 + wb0;

  // bpermute lane addresses + tile-select mask, per acc register r
  int bpaddr[4];
  bool loA[4];
#pragma unroll
  for (int r = 0; r < 4; r++) {
    int u = quad * 4 + r;
    bpaddr[r] = (((l15 + 15 - u) & 15) + 16 * quad) * 4;
    loA[r] = (l15 <= u);  // source tile nt (else nt+1)
  }

  bf16x8 aq0, aq1;
  {
    const bf16* qrow = qh + (size_t)(i0 + l15) * 64 + quad * 8;
    aq0 = *(const bf16x8*)qrow;
    aq1 = *(const bf16x8*)(qrow + 32);
  }
  bf16x8 ones;
#pragma unroll
  for (int j = 0; j < 8; j++) ones[j] = (bf16)1.0f;

  f32x4 O[4], Osum;
  Osum = (f32x4){0.f, 0.f, 0.f, 0.f};
#pragma unroll
  for (int i = 0; i < 4; i++) O[i] = (f32x4){0.f, 0.f, 0.f, 0.f};
  const float sc = 0.125f * 1.44269504088896f;  // 1/sqrt(64) * log2(e)
  const int ebase00 = 2047 - i0 - 15;

  // ---- carry init: T-tile c-range [0,16) of the first chunk tile ----
  float Bpc[4];
  {
    int er = ebase00 + jt0 * 64 + l15;
    er = er > 2047 ? 2047 : er;
    const bf16* erow = Eb + (size_t)er * 64 + quad * 8;
    bf16x8 e0 = *(const bf16x8*)erow;
    bf16x8 e1 = *(const bf16x8*)(erow + 32);
    f32x4 zz = (f32x4){0.f, 0.f, 0.f, 0.f};
    zz = MFMA16(aq0, e0, zz);
    zz = MFMA16(aq1, e1, zz);
#pragma unroll
    for (int r = 0; r < 4; r++)
      Bpc[r] = __int_as_float(__builtin_amdgcn_ds_bpermute(bpaddr[r], __float_as_int(zz[r])));
  }

  for (int jt = jt0; jt < jt1; jt++) {
    const int j0 = jt * 64;
    const bool diag = (jt == strip);  // only the last tile of A/B chunks
    __syncthreads();  // all waves done reading K/V of previous tile
    // ---- issue staging for this tile (async into LDS) ----
    gll16(kh + (size_t)(j0 + sr0) * 64 + sc0 * 8, (char*)Kl + wb0);
    gll16(kh + (size_t)(j0 + sr1) * 64 + sc0 * 8, (char*)Kl + wb1);
    gll16(vh + (size_t)sr0 * 2048 + j0 + sc0 * 8, (char*)Vl + wb0);
    gll16(vh + (size_t)sr1 * 2048 + j0 + sc0 * 8, (char*)Vl + wb1);
    // ---- E-band: fresh T-tiles nt=1..4 (nt=0 carried); overlaps staging ----
    float Bp[5][4];
#pragma unroll
    for (int r = 0; r < 4; r++) Bp[0][r] = Bpc[r];
    const int ebase = ebase00 + j0;
#pragma unroll
    for (int nt = 1; nt < 5; nt++) {
      int er = ebase + nt * 16 + l15;
      er = er > 2047 ? 2047 : er;  // clamped rows feed only masked entries
      const bf16* erow = Eb + (size_t)er * 64 + quad * 8;
      bf16x8 e0 = *(const bf16x8*)erow;
      bf16x8 e1 = *(const bf16x8*)(erow + 32);
      f32x4 zz = (f32x4){0.f, 0.f, 0.f, 0.f};
      zz = MFMA16(aq0, e0, zz);
      zz = MFMA16(aq1, e1, zz);
#pragma unroll
      for (int r = 0; r < 4; r++)
        Bp[nt][r] =
            __int_as_float(__builtin_amdgcn_ds_bpermute(bpaddr[r], __float_as_int(zz[r])));
    }
#pragma unroll
    for (int r = 0; r < 4; r++) Bpc[r] = Bp[4][r];

    __syncthreads();  // staging complete (vmcnt drained before barrier)
    // ---- S = q @ k^T from LDS (swizzled b128 reads) ----
    f32x4 s[4];
#pragma unroll
    for (int nt = 0; nt < 4; nt++) {
      int row = nt * 16 + l15;
      bf16x8 k0 = *(const bf16x8*)(Kl + ((row << 3) + (quad ^ (row & 7))) * 8);
      bf16x8 k1 = *(const bf16x8*)(Kl + ((row << 3) + ((quad + 4) ^ (row & 7))) * 8);
      f32x4 zz = (f32x4){0.f, 0.f, 0.f, 0.f};
      zz = MFMA16(aq0, k0, zz);
      s[nt] = MFMA16(aq1, k1, zz);
    }
    // ---- logits: skew add + scale (+ mask on diag tile) + exp2 + P ----
    if (diag) {
#pragma unroll
      for (int nt = 0; nt < 4; nt++)
#pragma unroll
        for (int r = 0; r < 4; r++) {
          int u = quad * 4 + r;
          int j = nt * 16 + l15;
          float skew = loA[r] ? Bp[nt][r] : Bp[nt + 1][r];
          float logit = (s[nt][r] + skew) * sc;
          if (j0 + j > i0 + u) logit = -1e30f;  // causal; exp2 -> 0
          Pw[u * 72 + j] = (bf16)EXP2F(logit);
        }
    } else {
#pragma unroll
      for (int nt = 0; nt < 4; nt++)
#pragma unroll
        for (int r = 0; r < 4; r++) {
          int u = quad * 4 + r;
          int j = nt * 16 + l15;
          float skew = loA[r] ? Bp[nt][r] : Bp[nt + 1][r];
          Pw[u * 72 + j] = (bf16)EXP2F((s[nt][r] + skew) * sc);
        }
    }
    // ---- PV: O += P @ V ; Osum += P @ ones ----
    bf16x8 pa0 = *(const bf16x8*)&Pw[l15 * 72 + quad * 8];
    bf16x8 pa1 = *(const bf16x8*)&Pw[l15 * 72 + 32 + quad * 8];
    Osum = MFMA16(pa0, ones, Osum);
    Osum = MFMA16(pa1, ones, Osum);
#pragma unroll
    for (int nt = 0; nt < 4; nt++) {
      int row = nt * 16 + l15;
      bf16x8 v0 = *(const bf16x8*)(Vl + ((row << 3) + (quad ^ (row & 7))) * 8);
      bf16x8 v1 = *(const bf16x8*)(Vl + ((row << 3) + ((quad + 4) ^ (row & 7))) * 8);
      O[nt] = MFMA16(pa0, v0, O[nt]);
      O[nt] = MFMA16(pa1, v1, O[nt]);
    }
  }
  // ---- epilogue ----
  if (isB) {
    // slot1 partial: unnormalized O + rowsum
    bf16* orow = Of1 + ((size_t)(bh * 1024 + (i0 - 1024))) * 64;
#pragma unroll
    for (int nt = 0; nt < 4; nt++)
#pragma unroll
      for (int r = 0; r < 4; r++)
        orow[(size_t)(quad * 4 + r) * 64 + nt * 16 + l15] = (bf16)O[nt][r];
    if (l15 == 0) {
#pragma unroll
      for (int r = 0; r < 4; r++) Os1[bh * 1024 + (i0 - 1024) + quad * 4 + r] = Osum[r];
    }
  } else if (strip < 16) {
    // COMPLETE job (single chunk, rows < 1024): normalize locally, no Os0.
    const int b = bh >> 3, hh = bh & 7;
    bf16* orow = attnb + ((size_t)(b * 2048 + i0)) * 512 + hh * 64;
    float inv[4];
#pragma unroll
    for (int r = 0; r < 4; r++) inv[r] = 1.0f / Osum[r];
#pragma unroll
    for (int nt = 0; nt < 4; nt++)
#pragma unroll
      for (int r = 0; r < 4; r++)
        orow[(size_t)(quad * 4 + r) * 512 + nt * 16 + l15] = (bf16)(O[nt][r] * inv[r]);
  } else {
    // slot0 partial (rows >= 1024): unnormalized O + rowsum
    const int b = bh >> 3, hh = bh & 7;
    bf16* orow = attnb + ((size_t)(b * 2048 + i0)) * 512 + hh * 64;
#pragma unroll
    for (int nt = 0; nt < 4; nt++)
#pragma unroll
      for (int r = 0; r < 4; r++)
        orow[(size_t)(quad * 4 + r) * 512 + nt * 16 + l15] = (bf16)O[nt][r];
    if (l15 == 0) {
#pragma unroll
      for (int r = 0; r < 4; r++) Os0[bh * 2048 + i0 + quad * 4 + r] = Osum[r];
    }
  }
}

// ---------------------------------------------------------------------------
// normalize rows l >= 1024 only (rows < 1024 normalized in attn epilogue):
// attnb = (slot0 + slot1) / (Os0 + Os1). 262144 vec8 -> grid 1024.
// ---------------------------------------------------------------------------
__global__ __launch_bounds__(256) void norm_kernel(bf16x8* __restrict__ attnb,
                                                   const bf16x8* __restrict__ Of1,
                                                   const float* __restrict__ Os0,
                                                   const float* __restrict__ Os1) {
  int i = blockIdx.x * 256 + threadIdx.x;  // vec8 index over rows >= 1024
  int col8 = i & 63;
  int rid = i >> 6;                        // 0..4095
  int b = rid >> 10, lo = rid & 1023;      // l = 1024 + lo
  int h = col8 >> 3, c8 = col8 & 7;
  int bh = b * 8 + h;
  float s = Os0[bh * 2048 + 1024 + lo] + Os1[bh * 1024 + lo];
  size_t ai = ((size_t)(b * 2048 + 1024 + lo)) * 64 + col8;
  bf16x8 v0 = attnb[ai];
  bf16x8 v1 = Of1[(size_t)(bh * 1024 + lo) * 8 + c8];
  float inv = 1.0f / s;
  bf16x8 o;
#pragma unroll
  for (int j = 0; j < 8; j++) o[j] = (bf16)(((float)v0[j] + (float)v1[j]) * inv);
  attnb[ai] = o;
}

// ---------------------------------------------------------------------------
extern "C" void kernel_launch(void* const* d_in, const int* in_sizes, int n_in,
                              void* d_out, int out_size, void* d_ws, size_t ws_size,
                              hipStream_t stream) {
  const float* Q = (const float*)d_in[0];
  const float* K = (const float*)d_in[1];
  const float* V = (const float*)d_in[2];
  const float* Wq = (const float*)d_in[4];
  const float* bq = (const float*)d_in[5];
  const float* Wk = (const float*)d_in[6];
  const float* bk = (const float*)d_in[7];
  const float* Wv = (const float*)d_in[8];
  const float* bv = (const float*)d_in[9];
  const float* fcw = (const float*)d_in[10];
  const float* fcb = (const float*)d_in[11];
  const float* E = (const float*)d_in[12];

  char* ws = (char*)d_ws;
  bf16* Wqb = (bf16*)(ws + 25165824);
  bf16* Wkb = (bf16*)(ws + 25690112);
  bf16* Wvb = (bf16*)(ws + 26214400);
  bf16* fcwb = (bf16*)(ws + 26738688);
  bf16* Eb = (bf16*)(ws + 27262976);
  bf16* qbuf = (bf16*)(ws + 27525120);
  bf16* kbuf = (bf16*)(ws + 35913728);
  bf16* vTb = (bf16*)(ws + 44302336);
  bf16* Of1 = (bf16*)(ws + 52690944);   // 32*1024*64 bf16 = 4 MiB
  float* Os0 = (float*)(ws + 56885248); // 32*2048 f32 = 256 KiB
  float* Os1 = (float*)(ws + 57147392); // 32*1024 f32 = 128 KiB
  bf16* attnb = (bf16*)(ws + 0);        // old Xq region

  convert_we<<<1152, 256, 0, stream>>>(
      (const float4*)Wq, (const float4*)Wk, (const float4*)Wv, (const float4*)fcw,
      (const float4*)E, (bf16x4*)Wqb, (bf16x4*)Wkb, (bf16x4*)Wvb, (bf16x4*)fcwb,
      (bf16x4*)Eb);

  proj_gemm<<<dim3(64, 8, 3), 256, 0, stream>>>(Q, K, V, Wqb, Wkb, Wvb, bq, bk, bv,
                                                qbuf, kbuf, vTb);

  attn_kernel<<<1536, 256, 0, stream>>>(qbuf, kbuf, vTb, Eb, attnb, Of1, Os0, Os1);

  norm_kernel<<<1024, 256, 0, stream>>>((bf16x8*)attnb, (const bf16x8*)Of1, Os0, Os1);

  final_gemm<<<dim3(128, 8), 256, 0, stream>>>(attnb, fcwb, fcb, (float*)d_out);
}

// Round 11
// 243.011 us; speedup vs baseline: 1.0358x; 1.0358x over previous
//
#include <hip/hip_runtime.h>
#include <stdint.h>

typedef __bf16 bf16;
typedef float f32x4 __attribute__((ext_vector_type(4)));
typedef bf16 bf16x8 __attribute__((ext_vector_type(8)));
typedef bf16 bf16x4 __attribute__((ext_vector_type(4)));

#define MFMA16(a, b, c) __builtin_amdgcn_mfma_f32_16x16x32_bf16((a), (b), (c), 0, 0, 0)
#define EXP2F(x) __builtin_amdgcn_exp2f(x)

__device__ __forceinline__ void gll16(const void* g, void* l) {
  __builtin_amdgcn_global_load_lds((const __attribute__((address_space(1))) void*)g,
                                   (__attribute__((address_space(3))) void*)l, 16, 0, 0);
}

// ---------------------------------------------------------------------------
// fp32 -> bf16 conversion of all tensors, one launch. (R10 lesson, twice
// falsified: folding fp32 into GEMM staging costs MORE than this pass.)
// ---------------------------------------------------------------------------
__global__ __launch_bounds__(256) void convert_all(
    const float4* __restrict__ Q, const float4* __restrict__ K, const float4* __restrict__ V,
    const float4* __restrict__ Wq, const float4* __restrict__ Wk, const float4* __restrict__ Wv,
    const float4* __restrict__ fcw, const float4* __restrict__ E,
    bf16x4* __restrict__ Xq, bf16x4* __restrict__ Xk, bf16x4* __restrict__ Xv,
    bf16x4* __restrict__ Wqb, bf16x4* __restrict__ Wkb, bf16x4* __restrict__ Wvb,
    bf16x4* __restrict__ fcb, bf16x4* __restrict__ Eb) {
  int i = blockIdx.x * 256 + threadIdx.x;
  const float4* s;
  bf16x4* d;
  int off;
  if (i < 1048576) { s = Q; d = Xq; off = i; }
  else if (i < 2097152) { s = K; d = Xk; off = i - 1048576; }
  else if (i < 3145728) { s = V; d = Xv; off = i - 2097152; }
  else if (i < 3211264) { s = Wq; d = Wqb; off = i - 3145728; }
  else if (i < 3276800) { s = Wk; d = Wkb; off = i - 3211264; }
  else if (i < 3342336) { s = Wv; d = Wvb; off = i - 3276800; }
  else if (i < 3407872) { s = fcw; d = fcb; off = i - 3342336; }
  else { s = E; d = Eb; off = i - 3407872; }
  float4 v = s[off];
  bf16x4 o;
  o[0] = (bf16)v.x; o[1] = (bf16)v.y; o[2] = (bf16)v.z; o[3] = (bf16)v.w;
  d[off] = o;
}

// ---------------------------------------------------------------------------
// GEMM core, 128x64 tile: C[128x64] = A[128x512] * Bt[64x512]^T (bf16).
// BK=32, proven staging. proj runs 6 blocks/CU (R9's validated occupancy win).
// Wave layout: 2x2 waves, wave tile 64 rows x 32 cols, acc[4][2].
// ---------------------------------------------------------------------------
__device__ __forceinline__ void gemm_core64(const bf16* __restrict__ A,
                                            const bf16* __restrict__ Bt, bf16* ldsA,
                                            bf16* ldsB, int m0, int n0, f32x4 acc[4][2]) {
  const int t = threadIdx.x;
  const int lane = t & 63, w = t >> 6;
  const int l15 = lane & 15, quad = lane >> 4;
  const int wm = w >> 1, wn = w & 1;
#pragma unroll
  for (int i = 0; i < 4; i++)
#pragma unroll
    for (int j = 0; j < 2; j++) acc[i][j] = (f32x4){0.f, 0.f, 0.f, 0.f};

  const int r0 = t >> 2, c0 = (t & 3) ^ (r0 & 3);
  const int r1 = r0 + 64;  // (r1&3)==(r0&3) so chunk xor is c0 for both

  int aoff[4], boff[2];
#pragma unroll
  for (int mt = 0; mt < 4; mt++) {
    int m = wm * 64 + mt * 16 + l15;
    aoff[mt] = (m << 6) + ((quad ^ (l15 & 3)) << 4);
  }
#pragma unroll
  for (int nt = 0; nt < 2; nt++) {
    int n = wn * 32 + nt * 16 + l15;
    boff[nt] = (n << 6) + ((quad ^ (l15 & 3)) << 4);
  }
  bf16* ldsA1 = ldsA + w * 512;
  bf16* ldsA2 = ldsA + 2048 + w * 512;
  bf16* ldsB1 = ldsB + w * 512;

  for (int kt = 0; kt < 512; kt += 32) {
    gll16(A + (size_t)(m0 + r0) * 512 + kt + c0 * 8, ldsA1);
    gll16(A + (size_t)(m0 + r1) * 512 + kt + c0 * 8, ldsA2);
    gll16(Bt + (size_t)(n0 + r0) * 512 + kt + c0 * 8, ldsB1);
    __syncthreads();
    bf16x8 af[4], bfr[2];
#pragma unroll
    for (int mt = 0; mt < 4; mt++) af[mt] = *(const bf16x8*)((const char*)ldsA + aoff[mt]);
#pragma unroll
    for (int nt = 0; nt < 2; nt++) bfr[nt] = *(const bf16x8*)((const char*)ldsB + boff[nt]);
#pragma unroll
    for (int mt = 0; mt < 4; mt++)
#pragma unroll
      for (int nt = 0; nt < 2; nt++)
        acc[mt][nt] = MFMA16(af[mt], bfr[nt], acc[mt][nt]);
    __syncthreads();
  }
}

// proj_gemm: 128x64 tiles, grid (64, 8, 3) = 1536 blocks (6/CU).
// z==0/1 write q/k in (B,H,L,64). z==2 (one head per block) writes v DIRECTLY
// TRANSPOSED into vT (B,H,64,L) via LDS-staged transpose, coalesced stores.
__global__ __launch_bounds__(256) void proj_gemm(
    const bf16* __restrict__ Xq, const bf16* __restrict__ Xk, const bf16* __restrict__ Xv,
    const bf16* __restrict__ Wq, const bf16* __restrict__ Wk, const bf16* __restrict__ Wv,
    const float* __restrict__ bq, const float* __restrict__ bk, const float* __restrict__ bv,
    bf16* __restrict__ qb, bf16* __restrict__ kb, bf16* __restrict__ vT) {
  __shared__ __align__(16) char smem[17408];  // gemm: 8KB A + 4KB B; transpose: 64x136
  bf16* ldsA = (bf16*)smem;
  bf16* ldsB = (bf16*)(smem + 8192);
  const int z = blockIdx.z;
  const bf16* A = z == 0 ? Xq : (z == 1 ? Xk : Xv);
  const bf16* W = z == 0 ? Wq : (z == 1 ? Wk : Wv);
  const float* bias = z == 0 ? bq : (z == 1 ? bk : bv);
  const int m0 = blockIdx.x * 128, n0 = blockIdx.y * 64;
  f32x4 acc[4][2];
  gemm_core64(A, W, ldsA, ldsB, m0, n0, acc);

  const int t = threadIdx.x;
  const int lane = t & 63, w = t >> 6;
  const int l15 = lane & 15, quad = lane >> 4;
  const int wm = w >> 1, wn = w & 1;
  if (z == 2) {
    // ---- transposed epilogue: this block covers ONE head (64 d-cols) ----
    bf16* T = (bf16*)smem;  // [64][136]
    const int b = m0 >> 11, l0 = m0 & 2047, h0 = blockIdx.y;
#pragma unroll
    for (int mt = 0; mt < 4; mt++)
#pragma unroll
      for (int nt = 0; nt < 2; nt++) {
        int d = wn * 32 + nt * 16 + l15;
        int lloc = wm * 64 + mt * 16 + quad * 4;
        float bi = bias[n0 + d];
        bf16x4 pv;
#pragma unroll
        for (int r = 0; r < 4; r++) pv[r] = (bf16)(acc[mt][nt][r] + bi);
        *(bf16x4*)&T[d * 136 + lloc] = pv;
      }
    __syncthreads();
    bf16* dsth = vT + ((size_t)((b * 8 + h0) * 64)) * 2048 + l0;
#pragma unroll
    for (int p = 0; p < 4; p++) {
      int id = t + 256 * p;  // 1024 chunks: 64 d-rows x 16 l-chunks of 8
      int d = id >> 4, c = id & 15;
      bf16x8 v = *(const bf16x8*)&T[d * 136 + c * 8];
      *(bf16x8*)&dsth[(size_t)d * 2048 + c * 8] = v;
    }
  } else {
    bf16* out = z == 0 ? qb : kb;
#pragma unroll
    for (int mt = 0; mt < 4; mt++)
#pragma unroll
      for (int nt = 0; nt < 2; nt++)
#pragma unroll
        for (int r = 0; r < 4; r++) {
          int gm = m0 + wm * 64 + mt * 16 + quad * 4 + r;
          int gn = n0 + wn * 32 + nt * 16 + l15;
          float v = acc[mt][nt][r] + bias[gn];
          int b = gm >> 11, l = gm & 2047, h = gn >> 6, d = gn & 63;
          out[(((size_t)(b * 8 + h)) * 2048 + l) * 64 + d] = (bf16)v;
        }
  }
}

// ---------------------------------------------------------------------------
// final_gemm: 64x64 tiles, grid (128, 8) = 1024 blocks (4/CU; was 2/CU in R9).
// Wave layout 2x2, wave tile 32x32, acc[2][2]; 1 gll16/side/kt.
// ---------------------------------------------------------------------------
__global__ __launch_bounds__(256) void final_gemm(const bf16* __restrict__ A,
                                                  const bf16* __restrict__ W,
                                                  const float* __restrict__ bias,
                                                  float* __restrict__ out) {
  __shared__ __align__(16) bf16 ldsA[64 * 32];
  __shared__ __align__(16) bf16 ldsB[64 * 32];
  const int m0 = blockIdx.x * 64, n0 = blockIdx.y * 64;
  const int t = threadIdx.x;
  const int lane = t & 63, w = t >> 6;
  const int l15 = lane & 15, quad = lane >> 4;
  const int wm = w >> 1, wn = w & 1;
  f32x4 acc[2][2];
#pragma unroll
  for (int i = 0; i < 2; i++)
#pragma unroll
    for (int j = 0; j < 2; j++) acc[i][j] = (f32x4){0.f, 0.f, 0.f, 0.f};

  const int r0 = t >> 2, c0 = (t & 3) ^ (r0 & 3);
  const int wbase = (t & 192) * 16;

  int aoff[2], boff[2];
#pragma unroll
  for (int mt = 0; mt < 2; mt++) {
    int m = wm * 32 + mt * 16 + l15;
    aoff[mt] = (m << 6) + ((quad ^ (m & 3)) << 4);
    int n = wn * 32 + mt * 16 + l15;
    boff[mt] = (n << 6) + ((quad ^ (n & 3)) << 4);
  }

  for (int kt = 0; kt < 512; kt += 32) {
    gll16(A + (size_t)(m0 + r0) * 512 + kt + c0 * 8, (char*)ldsA + wbase);
    gll16(W + (size_t)(n0 + r0) * 512 + kt + c0 * 8, (char*)ldsB + wbase);
    __syncthreads();
    bf16x8 af[2], bfr[2];
#pragma unroll
    for (int mt = 0; mt < 2; mt++) af[mt] = *(const bf16x8*)((const char*)ldsA + aoff[mt]);
#pragma unroll
    for (int nt = 0; nt < 2; nt++) bfr[nt] = *(const bf16x8*)((const char*)ldsB + boff[nt]);
#pragma unroll
    for (int mt = 0; mt < 2; mt++)
#pragma unroll
      for (int nt = 0; nt < 2; nt++)
        acc[mt][nt] = MFMA16(af[mt], bfr[nt], acc[mt][nt]);
    __syncthreads();
  }

#pragma unroll
  for (int mt = 0; mt < 2; mt++)
#pragma unroll
    for (int nt = 0; nt < 2; nt++)
#pragma unroll
      for (int r = 0; r < 4; r++) {
        int gm = m0 + wm * 32 + mt * 16 + quad * 4 + r;
        int gn = n0 + wn * 32 + nt * 16 + l15;
        out[(size_t)gm * 512 + gn] = acc[mt][nt][r] + bias[gn];
      }
}

// ---------------------------------------------------------------------------
// Flash attention + relative position, causal — R0 inner loop (~90us).
// Epilogue (R10-verified): COMPLETE jobs (strip<16 == rows l<1024, single
// chunk) normalize in-place by 1/Osum, no Os0 write. Rows >=1024 stay
// unnormalized, merged by the halved norm kernel.
// ---------------------------------------------------------------------------
__global__ __launch_bounds__(256, 4) void attn_kernel(
    const bf16* __restrict__ qbuf, const bf16* __restrict__ kbuf,
    const bf16* __restrict__ vT, const bf16* __restrict__ Eb,
    bf16* __restrict__ attnb, bf16* __restrict__ Of1,
    float* __restrict__ Os0, float* __restrict__ Os1) {
  __shared__ bf16 Kl[64 * 64];
  __shared__ bf16 Vl[64 * 64];
  __shared__ bf16 Pl[4][16 * 72];
  const int t = threadIdx.x, w = t >> 6, lane = t & 63;
  const int l15 = lane & 15, quad = lane >> 4;
  const int x = blockIdx.x;
  const int bh = x & 31, job = x >> 5;
  int strip, jt0, jt1;
  bool isB;
  if (job < 16) {
    strip = 16 + job; jt0 = 0; jt1 = 16; isB = false;
  } else {
    int k = job - 16, i = k >> 1;
    if ((k & 1) == 0) { strip = 15 - i; jt0 = 0; jt1 = 16 - i; isB = false; }
    else { strip = 31 - i; jt0 = 16; jt1 = 32 - i; isB = true; }
  }
  const int i0 = strip * 64 + w * 16;  // this wave's 16 q-rows
  bf16* Pw = Pl[w];
  const bf16* qh = qbuf + (size_t)bh * 2048 * 64;
  const bf16* kh = kbuf + (size_t)bh * 2048 * 64;
  const bf16* vh = vT + (size_t)bh * 64 * 2048;

  // staging: slot s holds (row = s>>3, chunk = (s&7)^(row&7)); thread t does
  // slots t and t+256; wave-uniform LDS byte base + lane*16B.
  const int sr0 = t >> 3, sc0 = (t & 7) ^ (sr0 & 7);
  const int sr1 = sr0 + 32;
  const int wb0 = (t & 192) * 16;  // byte offset of this wave's slot group
  const int wb1 = 4096 + wb0;

  // bpermute lane addresses + tile-select mask, per acc register r
  int bpaddr[4];
  bool loA[4];
#pragma unroll
  for (int r = 0; r < 4; r++) {
    int u = quad * 4 + r;
    bpaddr[r] = (((l15 + 15 - u) & 15) + 16 * quad) * 4;
    loA[r] = (l15 <= u);  // source tile nt (else nt+1)
  }

  bf16x8 aq0, aq1;
  {
    const bf16* qrow = qh + (size_t)(i0 + l15) * 64 + quad * 8;
    aq0 = *(const bf16x8*)qrow;
    aq1 = *(const bf16x8*)(qrow + 32);
  }
  bf16x8 ones;
#pragma unroll
  for (int j = 0; j < 8; j++) ones[j] = (bf16)1.0f;

  f32x4 O[4], Osum;
  Osum = (f32x4){0.f, 0.f, 0.f, 0.f};
#pragma unroll
  for (int i = 0; i < 4; i++) O[i] = (f32x4){0.f, 0.f, 0.f, 0.f};
  const float sc = 0.125f * 1.44269504088896f;  // 1/sqrt(64) * log2(e)
  const int ebase00 = 2047 - i0 - 15;

  // ---- carry init: T-tile c-range [0,16) of the first chunk tile ----
  float Bpc[4];
  {
    int er = ebase00 + jt0 * 64 + l15;
    er = er > 2047 ? 2047 : er;
    const bf16* erow = Eb + (size_t)er * 64 + quad * 8;
    bf16x8 e0 = *(const bf16x8*)erow;
    bf16x8 e1 = *(const bf16x8*)(erow + 32);
    f32x4 zz = (f32x4){0.f, 0.f, 0.f, 0.f};
    zz = MFMA16(aq0, e0, zz);
    zz = MFMA16(aq1, e1, zz);
#pragma unroll
    for (int r = 0; r < 4; r++)
      Bpc[r] = __int_as_float(__builtin_amdgcn_ds_bpermute(bpaddr[r], __float_as_int(zz[r])));
  }

  for (int jt = jt0; jt < jt1; jt++) {
    const int j0 = jt * 64;
    const bool diag = (jt == strip);  // only the last tile of A/B chunks
    __syncthreads();  // all waves done reading K/V of previous tile
    // ---- issue staging for this tile (async into LDS) ----
    gll16(kh + (size_t)(j0 + sr0) * 64 + sc0 * 8, (char*)Kl + wb0);
    gll16(kh + (size_t)(j0 + sr1) * 64 + sc0 * 8, (char*)Kl + wb1);
    gll16(vh + (size_t)sr0 * 2048 + j0 + sc0 * 8, (char*)Vl + wb0);
    gll16(vh + (size_t)sr1 * 2048 + j0 + sc0 * 8, (char*)Vl + wb1);
    // ---- E-band: fresh T-tiles nt=1..4 (nt=0 carried); overlaps staging ----
    float Bp[5][4];
#pragma unroll
    for (int r = 0; r < 4; r++) Bp[0][r] = Bpc[r];
    const int ebase = ebase00 + j0;
#pragma unroll
    for (int nt = 1; nt < 5; nt++) {
      int er = ebase + nt * 16 + l15;
      er = er > 2047 ? 2047 : er;  // clamped rows feed only masked entries
      const bf16* erow = Eb + (size_t)er * 64 + quad * 8;
      bf16x8 e0 = *(const bf16x8*)erow;
      bf16x8 e1 = *(const bf16x8*)(erow + 32);
      f32x4 zz = (f32x4){0.f, 0.f, 0.f, 0.f};
      zz = MFMA16(aq0, e0, zz);
      zz = MFMA16(aq1, e1, zz);
#pragma unroll
      for (int r = 0; r < 4; r++)
        Bp[nt][r] =
            __int_as_float(__builtin_amdgcn_ds_bpermute(bpaddr[r], __float_as_int(zz[r])));
    }
#pragma unroll
    for (int r = 0; r < 4; r++) Bpc[r] = Bp[4][r];

    __syncthreads();  // staging complete (vmcnt drained before barrier)
    // ---- S = q @ k^T from LDS (swizzled b128 reads) ----
    f32x4 s[4];
#pragma unroll
    for (int nt = 0; nt < 4; nt++) {
      int row = nt * 16 + l15;
      bf16x8 k0 = *(const bf16x8*)(Kl + ((row << 3) + (quad ^ (row & 7))) * 8);
      bf16x8 k1 = *(const bf16x8*)(Kl + ((row << 3) + ((quad + 4) ^ (row & 7))) * 8);
      f32x4 zz = (f32x4){0.f, 0.f, 0.f, 0.f};
      zz = MFMA16(aq0, k0, zz);
      s[nt] = MFMA16(aq1, k1, zz);
    }
    // ---- logits: skew add + scale (+ mask on diag tile) + exp2 + P ----
    if (diag) {
#pragma unroll
      for (int nt = 0; nt < 4; nt++)
#pragma unroll
        for (int r = 0; r < 4; r++) {
          int u = quad * 4 + r;
          int j = nt * 16 + l15;
          float skew = loA[r] ? Bp[nt][r] : Bp[nt + 1][r];
          float logit = (s[nt][r] + skew) * sc;
          if (j0 + j > i0 + u) logit = -1e30f;  // causal; exp2 -> 0
          Pw[u * 72 + j] = (bf16)EXP2F(logit);
        }
    } else {
#pragma unroll
      for (int nt = 0; nt < 4; nt++)
#pragma unroll
        for (int r = 0; r < 4; r++) {
          int u = quad * 4 + r;
          int j = nt * 16 + l15;
          float skew = loA[r] ? Bp[nt][r] : Bp[nt + 1][r];
          Pw[u * 72 + j] = (bf16)EXP2F((s[nt][r] + skew) * sc);
        }
    }
    // ---- PV: O += P @ V ; Osum += P @ ones ----
    bf16x8 pa0 = *(const bf16x8*)&Pw[l15 * 72 + quad * 8];
    bf16x8 pa1 = *(const bf16x8*)&Pw[l15 * 72 + 32 + quad * 8];
    Osum = MFMA16(pa0, ones, Osum);
    Osum = MFMA16(pa1, ones, Osum);
#pragma unroll
    for (int nt = 0; nt < 4; nt++) {
      int row = nt * 16 + l15;
      bf16x8 v0 = *(const bf16x8*)(Vl + ((row << 3) + (quad ^ (row & 7))) * 8);
      bf16x8 v1 = *(const bf16x8*)(Vl + ((row << 3) + ((quad + 4) ^ (row & 7))) * 8);
      O[nt] = MFMA16(pa0, v0, O[nt]);
      O[nt] = MFMA16(pa1, v1, O[nt]);
    }
  }
  // ---- epilogue ----
  if (isB) {
    // slot1 partial: unnormalized O + rowsum
    bf16* orow = Of1 + ((size_t)(bh * 1024 + (i0 - 1024))) * 64;
#pragma unroll
    for (int nt = 0; nt < 4; nt++)
#pragma unroll
      for (int r = 0; r < 4; r++)
        orow[(size_t)(quad * 4 + r) * 64 + nt * 16 + l15] = (bf16)O[nt][r];
    if (l15 == 0) {
#pragma unroll
      for (int r = 0; r < 4; r++) Os1[bh * 1024 + (i0 - 1024) + quad * 4 + r] = Osum[r];
    }
  } else if (strip < 16) {
    // COMPLETE job (single chunk, rows < 1024): normalize locally, no Os0.
    const int b = bh >> 3, hh = bh & 7;
    bf16* orow = attnb + ((size_t)(b * 2048 + i0)) * 512 + hh * 64;
    float inv[4];
#pragma unroll
    for (int r = 0; r < 4; r++) inv[r] = 1.0f / Osum[r];
#pragma unroll
    for (int nt = 0; nt < 4; nt++)
#pragma unroll
      for (int r = 0; r < 4; r++)
        orow[(size_t)(quad * 4 + r) * 512 + nt * 16 + l15] = (bf16)(O[nt][r] * inv[r]);
  } else {
    // slot0 partial (rows >= 1024): unnormalized O + rowsum
    const int b = bh >> 3, hh = bh & 7;
    bf16* orow = attnb + ((size_t)(b * 2048 + i0)) * 512 + hh * 64;
#pragma unroll
    for (int nt = 0; nt < 4; nt++)
#pragma unroll
      for (int r = 0; r < 4; r++)
        orow[(size_t)(quad * 4 + r) * 512 + nt * 16 + l15] = (bf16)O[nt][r];
    if (l15 == 0) {
#pragma unroll
      for (int r = 0; r < 4; r++) Os0[bh * 2048 + i0 + quad * 4 + r] = Osum[r];
    }
  }
}

// ---------------------------------------------------------------------------
// normalize rows l >= 1024 only (rows < 1024 normalized in attn epilogue):
// attnb = (slot0 + slot1) / (Os0 + Os1). 262144 vec8 -> grid 1024.
// ---------------------------------------------------------------------------
__global__ __launch_bounds__(256) void norm_kernel(bf16x8* __restrict__ attnb,
                                                   const bf16x8* __restrict__ Of1,
                                                   const float* __restrict__ Os0,
                                                   const float* __restrict__ Os1) {
  int i = blockIdx.x * 256 + threadIdx.x;  // vec8 index over rows >= 1024
  int col8 = i & 63;
  int rid = i >> 6;                        // 0..4095
  int b = rid >> 10, lo = rid & 1023;      // l = 1024 + lo
  int h = col8 >> 3, c8 = col8 & 7;
  int bh = b * 8 + h;
  float s = Os0[bh * 2048 + 1024 + lo] + Os1[bh * 1024 + lo];
  size_t ai = ((size_t)(b * 2048 + 1024 + lo)) * 64 + col8;
  bf16x8 v0 = attnb[ai];
  bf16x8 v1 = Of1[(size_t)(bh * 1024 + lo) * 8 + c8];
  float inv = 1.0f / s;
  bf16x8 o;
#pragma unroll
  for (int j = 0; j < 8; j++) o[j] = (bf16)(((float)v0[j] + (float)v1[j]) * inv);
  attnb[ai] = o;
}

// ---------------------------------------------------------------------------
extern "C" void kernel_launch(void* const* d_in, const int* in_sizes, int n_in,
                              void* d_out, int out_size, void* d_ws, size_t ws_size,
                              hipStream_t stream) {
  const float* Q = (const float*)d_in[0];
  const float* K = (const float*)d_in[1];
  const float* V = (const float*)d_in[2];
  const float* Wq = (const float*)d_in[4];
  const float* bq = (const float*)d_in[5];
  const float* Wk = (const float*)d_in[6];
  const float* bk = (const float*)d_in[7];
  const float* Wv = (const float*)d_in[8];
  const float* bv = (const float*)d_in[9];
  const float* fcw = (const float*)d_in[10];
  const float* fcb = (const float*)d_in[11];
  const float* E = (const float*)d_in[12];

  char* ws = (char*)d_ws;
  bf16* Xq = (bf16*)(ws + 0);
  bf16* Xk = (bf16*)(ws + 8388608);
  bf16* Xv = (bf16*)(ws + 16777216);
  bf16* Wqb = (bf16*)(ws + 25165824);
  bf16* Wkb = (bf16*)(ws + 25690112);
  bf16* Wvb = (bf16*)(ws + 26214400);
  bf16* fcwb = (bf16*)(ws + 26738688);
  bf16* Eb = (bf16*)(ws + 27262976);
  bf16* qbuf = (bf16*)(ws + 27525120);
  bf16* kbuf = (bf16*)(ws + 35913728);
  bf16* vTb = (bf16*)(ws + 44302336);   // old vbuf region: vT written directly
  bf16* Of1 = (bf16*)(ws + 52690944);   // 32*1024*64 bf16 = 4 MiB
  float* Os0 = (float*)(ws + 56885248); // 32*2048 f32 = 256 KiB
  float* Os1 = (float*)(ws + 57147392); // 32*1024 f32 = 128 KiB
  bf16* attnb = Xq;

  convert_all<<<13440, 256, 0, stream>>>(
      (const float4*)Q, (const float4*)K, (const float4*)V, (const float4*)Wq,
      (const float4*)Wk, (const float4*)Wv, (const float4*)fcw, (const float4*)E,
      (bf16x4*)Xq, (bf16x4*)Xk, (bf16x4*)Xv, (bf16x4*)Wqb, (bf16x4*)Wkb,
      (bf16x4*)Wvb, (bf16x4*)fcwb, (bf16x4*)Eb);

  proj_gemm<<<dim3(64, 8, 3), 256, 0, stream>>>(Xq, Xk, Xv, Wqb, Wkb, Wvb, bq, bk, bv,
                                                qbuf, kbuf, vTb);

  attn_kernel<<<1536, 256, 0, stream>>>(qbuf, kbuf, vTb, Eb, attnb, Of1, Os0, Os1);

  norm_kernel<<<1024, 256, 0, stream>>>((bf16x8*)attnb, (const bf16x8*)Of1, Os0, Os1);

  final_gemm<<<dim3(128, 8), 256, 0, stream>>>(attnb, fcwb, fcb, (float*)d_out);
}

// Round 12
// 241.827 us; speedup vs baseline: 1.0408x; 1.0049x over previous
//
#include <hip/hip_runtime.h>
#include <stdint.h>

typedef __bf16 bf16;
typedef float f32x4 __attribute__((ext_vector_type(4)));
typedef bf16 bf16x8 __attribute__((ext_vector_type(8)));
typedef bf16 bf16x4 __attribute__((ext_vector_type(4)));

#define MFMA16(a, b, c) __builtin_amdgcn_mfma_f32_16x16x32_bf16((a), (b), (c), 0, 0, 0)
#define EXP2F(x) __builtin_amdgcn_exp2f(x)

__device__ __forceinline__ void gll16(const void* g, void* l) {
  __builtin_amdgcn_global_load_lds((const __attribute__((address_space(1))) void*)g,
                                   (__attribute__((address_space(3))) void*)l, 16, 0, 0);
}

// ---------------------------------------------------------------------------
// fp32 -> bf16 conversion of all tensors, one launch. (Triple-falsified:
// folding fp32 into GEMM staging always costs more than this pass.)
// ---------------------------------------------------------------------------
__global__ __launch_bounds__(256) void convert_all(
    const float4* __restrict__ Q, const float4* __restrict__ K, const float4* __restrict__ V,
    const float4* __restrict__ Wq, const float4* __restrict__ Wk, const float4* __restrict__ Wv,
    const float4* __restrict__ fcw, const float4* __restrict__ E,
    bf16x4* __restrict__ Xq, bf16x4* __restrict__ Xk, bf16x4* __restrict__ Xv,
    bf16x4* __restrict__ Wqb, bf16x4* __restrict__ Wkb, bf16x4* __restrict__ Wvb,
    bf16x4* __restrict__ fcb, bf16x4* __restrict__ Eb) {
  int i = blockIdx.x * 256 + threadIdx.x;
  const float4* s;
  bf16x4* d;
  int off;
  if (i < 1048576) { s = Q; d = Xq; off = i; }
  else if (i < 2097152) { s = K; d = Xk; off = i - 1048576; }
  else if (i < 3145728) { s = V; d = Xv; off = i - 2097152; }
  else if (i < 3211264) { s = Wq; d = Wqb; off = i - 3145728; }
  else if (i < 3276800) { s = Wk; d = Wkb; off = i - 3211264; }
  else if (i < 3342336) { s = Wv; d = Wvb; off = i - 3276800; }
  else if (i < 3407872) { s = fcw; d = fcb; off = i - 3342336; }
  else { s = E; d = Eb; off = i - 3407872; }
  float4 v = s[off];
  bf16x4 o;
  o[0] = (bf16)v.x; o[1] = (bf16)v.y; o[2] = (bf16)v.z; o[3] = (bf16)v.w;
  d[off] = o;
}

// ---------------------------------------------------------------------------
// GEMM core, 64x64 tile: C[64x64] = A[64x512] * Bt[64x512]^T (bf16), BK=32.
// 1 gll16/side/kt; 8KB LDS; wave layout 2x2, wave tile 32x32, acc[2][2].
// Shared by proj (8 blocks/CU resident, wave-slot-limited) and final.
// ---------------------------------------------------------------------------
__device__ __forceinline__ void gemm64(const bf16* __restrict__ A,
                                       const bf16* __restrict__ Bt, char* ldsA, char* ldsB,
                                       int m0, int n0, f32x4 acc[2][2]) {
  const int t = threadIdx.x;
  const int lane = t & 63;
  const int l15 = lane & 15, quad = lane >> 4;
  const int w = t >> 6;
  const int wm = w >> 1, wn = w & 1;
#pragma unroll
  for (int i = 0; i < 2; i++)
#pragma unroll
    for (int j = 0; j < 2; j++) acc[i][j] = (f32x4){0.f, 0.f, 0.f, 0.f};

  const int r0 = t >> 2, c0 = (t & 3) ^ (r0 & 3);
  const int wbase = (t & 192) * 16;  // wave-uniform LDS base (+lane*16 by HW)

  int aoff[2], boff[2];
#pragma unroll
  for (int mt = 0; mt < 2; mt++) {
    int m = wm * 32 + mt * 16 + l15;
    aoff[mt] = (m << 6) + ((quad ^ (m & 3)) << 4);
    int n = wn * 32 + mt * 16 + l15;
    boff[mt] = (n << 6) + ((quad ^ (n & 3)) << 4);
  }

  for (int kt = 0; kt < 512; kt += 32) {
    gll16(A + (size_t)(m0 + r0) * 512 + kt + c0 * 8, ldsA + wbase);
    gll16(Bt + (size_t)(n0 + r0) * 512 + kt + c0 * 8, ldsB + wbase);
    __syncthreads();
    bf16x8 af[2], bfr[2];
#pragma unroll
    for (int mt = 0; mt < 2; mt++) af[mt] = *(const bf16x8*)(ldsA + aoff[mt]);
#pragma unroll
    for (int nt = 0; nt < 2; nt++) bfr[nt] = *(const bf16x8*)(ldsB + boff[nt]);
#pragma unroll
    for (int mt = 0; mt < 2; mt++)
#pragma unroll
      for (int nt = 0; nt < 2; nt++)
        acc[mt][nt] = MFMA16(af[mt], bfr[nt], acc[mt][nt]);
    __syncthreads();
  }
}

// proj_gemm: 64x64 tiles, grid (128, 8, 3) = 3072 blocks (8/CU resident).
// z==0/1 write q/k in (B,H,L,64). z==2 (one head per block) writes v DIRECTLY
// TRANSPOSED into vT (B,H,64,L) via a 9.2KB LDS transpose, coalesced stores.
__global__ __launch_bounds__(256) void proj_gemm(
    const bf16* __restrict__ Xq, const bf16* __restrict__ Xk, const bf16* __restrict__ Xv,
    const bf16* __restrict__ Wq, const bf16* __restrict__ Wk, const bf16* __restrict__ Wv,
    const float* __restrict__ bq, const float* __restrict__ bk, const float* __restrict__ bv,
    bf16* __restrict__ qb, bf16* __restrict__ kb, bf16* __restrict__ vT) {
  __shared__ __align__(16) char smem[9216];  // gemm: 4KB A + 4KB B; transpose: 64x72 bf16
  char* ldsA = smem;
  char* ldsB = smem + 4096;
  const int z = blockIdx.z;
  const bf16* A = z == 0 ? Xq : (z == 1 ? Xk : Xv);
  const bf16* W = z == 0 ? Wq : (z == 1 ? Wk : Wv);
  const float* bias = z == 0 ? bq : (z == 1 ? bk : bv);
  const int m0 = blockIdx.x * 64, n0 = blockIdx.y * 64;
  f32x4 acc[2][2];
  gemm64(A, W, ldsA, ldsB, m0, n0, acc);

  const int t = threadIdx.x;
  const int lane = t & 63, w = t >> 6;
  const int l15 = lane & 15, quad = lane >> 4;
  const int wm = w >> 1, wn = w & 1;
  if (z == 2) {
    // ---- transposed epilogue: this block = ONE head x 64 l-rows ----
    bf16* T = (bf16*)smem;  // [64][72]
    const int b = m0 >> 11, l0 = m0 & 2047, h0 = blockIdx.y;
#pragma unroll
    for (int mt = 0; mt < 2; mt++)
#pragma unroll
      for (int nt = 0; nt < 2; nt++) {
        int d = wn * 32 + nt * 16 + l15;
        int lloc = wm * 32 + mt * 16 + quad * 4;
        float bi = bias[n0 + d];
        bf16x4 pv;
#pragma unroll
        for (int r = 0; r < 4; r++) pv[r] = (bf16)(acc[mt][nt][r] + bi);
        *(bf16x4*)&T[d * 72 + lloc] = pv;
      }
    __syncthreads();
    bf16* dsth = vT + ((size_t)((b * 8 + h0) * 64)) * 2048 + l0;
#pragma unroll
    for (int p = 0; p < 2; p++) {
      int id = t + 256 * p;  // 512 chunks: 64 d-rows x 8 l-chunks of 8
      int d = id >> 3, c = id & 7;
      bf16x8 v = *(const bf16x8*)&T[d * 72 + c * 8];
      *(bf16x8*)&dsth[(size_t)d * 2048 + c * 8] = v;
    }
  } else {
    bf16* out = z == 0 ? qb : kb;
#pragma unroll
    for (int mt = 0; mt < 2; mt++)
#pragma unroll
      for (int nt = 0; nt < 2; nt++)
#pragma unroll
        for (int r = 0; r < 4; r++) {
          int gm = m0 + wm * 32 + mt * 16 + quad * 4 + r;
          int gn = n0 + wn * 32 + nt * 16 + l15;
          float v = acc[mt][nt][r] + bias[gn];
          int b = gm >> 11, l = gm & 2047, h = gn >> 6, d = gn & 63;
          out[(((size_t)(b * 8 + h)) * 2048 + l) * 64 + d] = (bf16)v;
        }
  }
}

// final_gemm: 64x64 tiles, grid (128, 8) = 1024 blocks (R11-validated).
__global__ __launch_bounds__(256) void final_gemm(const bf16* __restrict__ A,
                                                  const bf16* __restrict__ W,
                                                  const float* __restrict__ bias,
                                                  float* __restrict__ out) {
  __shared__ __align__(16) char smem[8192];
  const int m0 = blockIdx.x * 64, n0 = blockIdx.y * 64;
  f32x4 acc[2][2];
  gemm64(A, W, smem, smem + 4096, m0, n0, acc);

  const int t = threadIdx.x;
  const int lane = t & 63, w = t >> 6;
  const int l15 = lane & 15, quad = lane >> 4;
  const int wm = w >> 1, wn = w & 1;
#pragma unroll
  for (int mt = 0; mt < 2; mt++)
#pragma unroll
    for (int nt = 0; nt < 2; nt++)
#pragma unroll
      for (int r = 0; r < 4; r++) {
        int gm = m0 + wm * 32 + mt * 16 + quad * 4 + r;
        int gn = n0 + wn * 32 + nt * 16 + l15;
        out[(size_t)gm * 512 + gn] = acc[mt][nt][r] + bias[gn];
      }
}

// ---------------------------------------------------------------------------
// Flash attention + relative position, causal — R0 inner loop (~90us).
// Epilogue (R10/R11-verified): COMPLETE jobs (strip<16 == rows l<1024,
// single chunk) normalize in-place by 1/Osum, no Os0 write. Rows >=1024
// stay unnormalized, merged by the halved norm kernel.
// ---------------------------------------------------------------------------
__global__ __launch_bounds__(256, 4) void attn_kernel(
    const bf16* __restrict__ qbuf, const bf16* __restrict__ kbuf,
    const bf16* __restrict__ vT, const bf16* __restrict__ Eb,
    bf16* __restrict__ attnb, bf16* __restrict__ Of1,
    float* __restrict__ Os0, float* __restrict__ Os1) {
  __shared__ bf16 Kl[64 * 64];
  __shared__ bf16 Vl[64 * 64];
  __shared__ bf16 Pl[4][16 * 72];
  const int t = threadIdx.x, w = t >> 6, lane = t & 63;
  const int l15 = lane & 15, quad = lane >> 4;
  const int x = blockIdx.x;
  const int bh = x & 31, job = x >> 5;
  int strip, jt0, jt1;
  bool isB;
  if (job < 16) {
    strip = 16 + job; jt0 = 0; jt1 = 16; isB = false;
  } else {
    int k = job - 16, i = k >> 1;
    if ((k & 1) == 0) { strip = 15 - i; jt0 = 0; jt1 = 16 - i; isB = false; }
    else { strip = 31 - i; jt0 = 16; jt1 = 32 - i; isB = true; }
  }
  const int i0 = strip * 64 + w * 16;  // this wave's 16 q-rows
  bf16* Pw = Pl[w];
  const bf16* qh = qbuf + (size_t)bh * 2048 * 64;
  const bf16* kh = kbuf + (size_t)bh * 2048 * 64;
  const bf16* vh = vT + (size_t)bh * 64 * 2048;

  // staging: slot s holds (row = s>>3, chunk = (s&7)^(row&7)); thread t does
  // slots t and t+256; wave-uniform LDS byte base + lane*16B.
  const int sr0 = t >> 3, sc0 = (t & 7) ^ (sr0 & 7);
  const int sr1 = sr0 + 32;
  const int wb0 = (t & 192) * 16;  // byte offset of this wave's slot group
  const int wb1 = 4096 + wb0;

  // bpermute lane addresses + tile-select mask, per acc register r
  int bpaddr[4];
  bool loA[4];
#pragma unroll
  for (int r = 0; r < 4; r++) {
    int u = quad * 4 + r;
    bpaddr[r] = (((l15 + 15 - u) & 15) + 16 * quad) * 4;
    loA[r] = (l15 <= u);  // source tile nt (else nt+1)
  }

  bf16x8 aq0, aq1;
  {
    const bf16* qrow = qh + (size_t)(i0 + l15) * 64 + quad * 8;
    aq0 = *(const bf16x8*)qrow;
    aq1 = *(const bf16x8*)(qrow + 32);
  }
  bf16x8 ones;
#pragma unroll
  for (int j = 0; j < 8; j++) ones[j] = (bf16)1.0f;

  f32x4 O[4], Osum;
  Osum = (f32x4){0.f, 0.f, 0.f, 0.f};
#pragma unroll
  for (int i = 0; i < 4; i++) O[i] = (f32x4){0.f, 0.f, 0.f, 0.f};
  const float sc = 0.125f * 1.44269504088896f;  // 1/sqrt(64) * log2(e)
  const int ebase00 = 2047 - i0 - 15;

  // ---- carry init: T-tile c-range [0,16) of the first chunk tile ----
  float Bpc[4];
  {
    int er = ebase00 + jt0 * 64 + l15;
    er = er > 2047 ? 2047 : er;
    const bf16* erow = Eb + (size_t)er * 64 + quad * 8;
    bf16x8 e0 = *(const bf16x8*)erow;
    bf16x8 e1 = *(const bf16x8*)(erow + 32);
    f32x4 zz = (f32x4){0.f, 0.f, 0.f, 0.f};
    zz = MFMA16(aq0, e0, zz);
    zz = MFMA16(aq1, e1, zz);
#pragma unroll
    for (int r = 0; r < 4; r++)
      Bpc[r] = __int_as_float(__builtin_amdgcn_ds_bpermute(bpaddr[r], __float_as_int(zz[r])));
  }

  for (int jt = jt0; jt < jt1; jt++) {
    const int j0 = jt * 64;
    const bool diag = (jt == strip);  // only the last tile of A/B chunks
    __syncthreads();  // all waves done reading K/V of previous tile
    // ---- issue staging for this tile (async into LDS) ----
    gll16(kh + (size_t)(j0 + sr0) * 64 + sc0 * 8, (char*)Kl + wb0);
    gll16(kh + (size_t)(j0 + sr1) * 64 + sc0 * 8, (char*)Kl + wb1);
    gll16(vh + (size_t)sr0 * 2048 + j0 + sc0 * 8, (char*)Vl + wb0);
    gll16(vh + (size_t)sr1 * 2048 + j0 + sc0 * 8, (char*)Vl + wb1);
    // ---- E-band: fresh T-tiles nt=1..4 (nt=0 carried); overlaps staging ----
    float Bp[5][4];
#pragma unroll
    for (int r = 0; r < 4; r++) Bp[0][r] = Bpc[r];
    const int ebase = ebase00 + j0;
#pragma unroll
    for (int nt = 1; nt < 5; nt++) {
      int er = ebase + nt * 16 + l15;
      er = er > 2047 ? 2047 : er;  // clamped rows feed only masked entries
      const bf16* erow = Eb + (size_t)er * 64 + quad * 8;
      bf16x8 e0 = *(const bf16x8*)erow;
      bf16x8 e1 = *(const bf16x8*)(erow + 32);
      f32x4 zz = (f32x4){0.f, 0.f, 0.f, 0.f};
      zz = MFMA16(aq0, e0, zz);
      zz = MFMA16(aq1, e1, zz);
#pragma unroll
      for (int r = 0; r < 4; r++)
        Bp[nt][r] =
            __int_as_float(__builtin_amdgcn_ds_bpermute(bpaddr[r], __float_as_int(zz[r])));
    }
#pragma unroll
    for (int r = 0; r < 4; r++) Bpc[r] = Bp[4][r];

    __syncthreads();  // staging complete (vmcnt drained before barrier)
    // ---- S = q @ k^T from LDS (swizzled b128 reads) ----
    f32x4 s[4];
#pragma unroll
    for (int nt = 0; nt < 4; nt++) {
      int row = nt * 16 + l15;
      bf16x8 k0 = *(const bf16x8*)(Kl + ((row << 3) + (quad ^ (row & 7))) * 8);
      bf16x8 k1 = *(const bf16x8*)(Kl + ((row << 3) + ((quad + 4) ^ (row & 7))) * 8);
      f32x4 zz = (f32x4){0.f, 0.f, 0.f, 0.f};
      zz = MFMA16(aq0, k0, zz);
      s[nt] = MFMA16(aq1, k1, zz);
    }
    // ---- logits: skew add + scale (+ mask on diag tile) + exp2 + P ----
    if (diag) {
#pragma unroll
      for (int nt = 0; nt < 4; nt++)
#pragma unroll
        for (int r = 0; r < 4; r++) {
          int u = quad * 4 + r;
          int j = nt * 16 + l15;
          float skew = loA[r] ? Bp[nt][r] : Bp[nt + 1][r];
          float logit = (s[nt][r] + skew) * sc;
          if (j0 + j > i0 + u) logit = -1e30f;  // causal; exp2 -> 0
          Pw[u * 72 + j] = (bf16)EXP2F(logit);
        }
    } else {
#pragma unroll
      for (int nt = 0; nt < 4; nt++)
#pragma unroll
        for (int r = 0; r < 4; r++) {
          int u = quad * 4 + r;
          int j = nt * 16 + l15;
          float skew = loA[r] ? Bp[nt][r] : Bp[nt + 1][r];
          Pw[u * 72 + j] = (bf16)EXP2F((s[nt][r] + skew) * sc);
        }
    }
    // ---- PV: O += P @ V ; Osum += P @ ones ----
    bf16x8 pa0 = *(const bf16x8*)&Pw[l15 * 72 + quad * 8];
    bf16x8 pa1 = *(const bf16x8*)&Pw[l15 * 72 + 32 + quad * 8];
    Osum = MFMA16(pa0, ones, Osum);
    Osum = MFMA16(pa1, ones, Osum);
#pragma unroll
    for (int nt = 0; nt < 4; nt++) {
      int row = nt * 16 + l15;
      bf16x8 v0 = *(const bf16x8*)(Vl + ((row << 3) + (quad ^ (row & 7))) * 8);
      bf16x8 v1 = *(const bf16x8*)(Vl + ((row << 3) + ((quad + 4) ^ (row & 7))) * 8);
      O[nt] = MFMA16(pa0, v0, O[nt]);
      O[nt] = MFMA16(pa1, v1, O[nt]);
    }
  }
  // ---- epilogue ----
  if (isB) {
    // slot1 partial: unnormalized O + rowsum
    bf16* orow = Of1 + ((size_t)(bh * 1024 + (i0 - 1024))) * 64;
#pragma unroll
    for (int nt = 0; nt < 4; nt++)
#pragma unroll
      for (int r = 0; r < 4; r++)
        orow[(size_t)(quad * 4 + r) * 64 + nt * 16 + l15] = (bf16)O[nt][r];
    if (l15 == 0) {
#pragma unroll
      for (int r = 0; r < 4; r++) Os1[bh * 1024 + (i0 - 1024) + quad * 4 + r] = Osum[r];
    }
  } else if (strip < 16) {
    // COMPLETE job (single chunk, rows < 1024): normalize locally, no Os0.
    const int b = bh >> 3, hh = bh & 7;
    bf16* orow = attnb + ((size_t)(b * 2048 + i0)) * 512 + hh * 64;
    float inv[4];
#pragma unroll
    for (int r = 0; r < 4; r++) inv[r] = 1.0f / Osum[r];
#pragma unroll
    for (int nt = 0; nt < 4; nt++)
#pragma unroll
      for (int r = 0; r < 4; r++)
        orow[(size_t)(quad * 4 + r) * 512 + nt * 16 + l15] = (bf16)(O[nt][r] * inv[r]);
  } else {
    // slot0 partial (rows >= 1024): unnormalized O + rowsum
    const int b = bh >> 3, hh = bh & 7;
    bf16* orow = attnb + ((size_t)(b * 2048 + i0)) * 512 + hh * 64;
#pragma unroll
    for (int nt = 0; nt < 4; nt++)
#pragma unroll
      for (int r = 0; r < 4; r++)
        orow[(size_t)(quad * 4 + r) * 512 + nt * 16 + l15] = (bf16)O[nt][r];
    if (l15 == 0) {
#pragma unroll
      for (int r = 0; r < 4; r++) Os0[bh * 2048 + i0 + quad * 4 + r] = Osum[r];
    }
  }
}

// ---------------------------------------------------------------------------
// normalize rows l >= 1024 only (rows < 1024 normalized in attn epilogue):
// attnb = (slot0 + slot1) / (Os0 + Os1). 262144 vec8 -> grid 1024.
// ---------------------------------------------------------------------------
__global__ __launch_bounds__(256) void norm_kernel(bf16x8* __restrict__ attnb,
                                                   const bf16x8* __restrict__ Of1,
                                                   const float* __restrict__ Os0,
                                                   const float* __restrict__ Os1) {
  int i = blockIdx.x * 256 + threadIdx.x;  // vec8 index over rows >= 1024
  int col8 = i & 63;
  int rid = i >> 6;                        // 0..4095
  int b = rid >> 10, lo = rid & 1023;      // l = 1024 + lo
  int h = col8 >> 3, c8 = col8 & 7;
  int bh = b * 8 + h;
  float s = Os0[bh * 2048 + 1024 + lo] + Os1[bh * 1024 + lo];
  size_t ai = ((size_t)(b * 2048 + 1024 + lo)) * 64 + col8;
  bf16x8 v0 = attnb[ai];
  bf16x8 v1 = Of1[(size_t)(bh * 1024 + lo) * 8 + c8];
  float inv = 1.0f / s;
  bf16x8 o;
#pragma unroll
  for (int j = 0; j < 8; j++) o[j] = (bf16)(((float)v0[j] + (float)v1[j]) * inv);
  attnb[ai] = o;
}

// ---------------------------------------------------------------------------
extern "C" void kernel_launch(void* const* d_in, const int* in_sizes, int n_in,
                              void* d_out, int out_size, void* d_ws, size_t ws_size,
                              hipStream_t stream) {
  const float* Q = (const float*)d_in[0];
  const float* K = (const float*)d_in[1];
  const float* V = (const float*)d_in[2];
  const float* Wq = (const float*)d_in[4];
  const float* bq = (const float*)d_in[5];
  const float* Wk = (const float*)d_in[6];
  const float* bk = (const float*)d_in[7];
  const float* Wv = (const float*)d_in[8];
  const float* bv = (const float*)d_in[9];
  const float* fcw = (const float*)d_in[10];
  const float* fcb = (const float*)d_in[11];
  const float* E = (const float*)d_in[12];

  char* ws = (char*)d_ws;
  bf16* Xq = (bf16*)(ws + 0);
  bf16* Xk = (bf16*)(ws + 8388608);
  bf16* Xv = (bf16*)(ws + 16777216);
  bf16* Wqb = (bf16*)(ws + 25165824);
  bf16* Wkb = (bf16*)(ws + 25690112);
  bf16* Wvb = (bf16*)(ws + 26214400);
  bf16* fcwb = (bf16*)(ws + 26738688);
  bf16* Eb = (bf16*)(ws + 27262976);
  bf16* qbuf = (bf16*)(ws + 27525120);
  bf16* kbuf = (bf16*)(ws + 35913728);
  bf16* vTb = (bf16*)(ws + 44302336);   // vT written directly by proj z==2
  bf16* Of1 = (bf16*)(ws + 52690944);   // 32*1024*64 bf16 = 4 MiB
  float* Os0 = (float*)(ws + 56885248); // 32*2048 f32 = 256 KiB
  float* Os1 = (float*)(ws + 57147392); // 32*1024 f32 = 128 KiB
  bf16* attnb = Xq;

  convert_all<<<13440, 256, 0, stream>>>(
      (const float4*)Q, (const float4*)K, (const float4*)V, (const float4*)Wq,
      (const float4*)Wk, (const float4*)Wv, (const float4*)fcw, (const float4*)E,
      (bf16x4*)Xq, (bf16x4*)Xk, (bf16x4*)Xv, (bf16x4*)Wqb, (bf16x4*)Wkb,
      (bf16x4*)Wvb, (bf16x4*)fcwb, (bf16x4*)Eb);

  proj_gemm<<<dim3(128, 8, 3), 256, 0, stream>>>(Xq, Xk, Xv, Wqb, Wkb, Wvb, bq, bk, bv,
                                                 qbuf, kbuf, vTb);

  attn_kernel<<<1536, 256, 0, stream>>>(qbuf, kbuf, vTb, Eb, attnb, Of1, Os0, Os1);

  norm_kernel<<<1024, 256, 0, stream>>>((bf16x8*)attnb, (const bf16x8*)Of1, Os0, Os1);

  final_gemm<<<dim3(128, 8), 256, 0, stream>>>(attnb, fcwb, fcb, (float*)d_out);
}